// Round 9
// baseline (1194.199 us; speedup 1.0000x reference)
//
#include <hip/hip_runtime.h>
#include <math.h>

#define HH 4096
#define WW 4096
#define R 4             // rows per lane
#define NBLK 16         // 4096 / (64*R)
#define U 8
#define NGR (WW / U)    // 512 groups
#define GATE 64         // consumer starts once producer published column GATE

// halo slots: halo[(blk*WW + col)*2 + s]; s=0 -> producer row rb+254 (consumer
// r-2), s=1 -> row rb+255 (r-1). Value after column col-1 (col=0 = initial x).
// Entry: low32 = float bits, high32 = tag (col+1). Poison never matches tags.

__device__ __forceinline__ float f4c(const float4& v, int k) {
    return (k == 0) ? v.x : ((k == 1) ? v.y : ((k == 2) ? v.z : v.w));
}

// shift all 64 lanes down by 1 at VALU speed; lane 0 receives fill's lane-0 value.
__device__ __forceinline__ float wave_shr1(float src, float fill) {
    return __int_as_float(__builtin_amdgcn_update_dpp(
        __float_as_int(fill), __float_as_int(src), 0x138, 0xF, 0xF, false));
}

// HW sin: v_sin_f32 computes sin(2*pi*x). |z| <= 3 -> no range reduction.
__device__ __forceinline__ float fast_sin(float z) {
    return __builtin_amdgcn_sinf(z * 0.15915494309189535f);  // 1/(2*pi)
}

// W[6] = w rows rb-2..rb+3, B[4] = b rows rb..rb+3 for this column.
// Old activations: d2,d1 = rows rb-2,rb-1 (from DPP/halo); a0..a3 = rb..rb+3.
#define COLSTEP(COL, M, K)                                                   \
    do {                                                                     \
        const float d1 = wave_shr1(a3, Hhi[M][K]);                           \
        const float d2 = wave_shr1(a2, Hlo[M][K]);                           \
        const float w0v = f4c(Wr[M][0][(K) >> 2], (K) & 3);                  \
        const float w1v = f4c(Wr[M][1][(K) >> 2], (K) & 3);                  \
        const float w2v = f4c(Wr[M][2][(K) >> 2], (K) & 3);                  \
        const float w3v = f4c(Wr[M][3][(K) >> 2], (K) & 3);                  \
        const float w4v = f4c(Wr[M][4][(K) >> 2], (K) & 3);                  \
        const float w5v = f4c(Wr[M][5][(K) >> 2], (K) & 3);                  \
        const float n0 = fast_sin(fmaf(d2, w0v, fmaf(d1, w1v,               \
                          fmaf(a0, w2v, f4c(Br[M][0][(K) >> 2], (K) & 3))))); \
        const float n1 = fast_sin(fmaf(d1, w1v, fmaf(a0, w2v,               \
                          fmaf(a1, w3v, f4c(Br[M][1][(K) >> 2], (K) & 3))))); \
        const float n2 = fast_sin(fmaf(a0, w2v, fmaf(a1, w3v,               \
                          fmaf(a2, w4v, f4c(Br[M][2][(K) >> 2], (K) & 3))))); \
        const float n3 = fast_sin(fmaf(a1, w3v, fmaf(a2, w4v,               \
                          fmaf(a3, w5v, f4c(Br[M][3][(K) >> 2], (K) & 3))))); \
        a0 = n0; a1 = n1; a2 = n2; a3 = n3;                                  \
        if (lane == 63 && (COL) + 1 < WW) {                                  \
            const unsigned long long tg =                                    \
                ((unsigned long long)(unsigned)((COL) + 2) << 32);           \
            atomicExch(&hme[(size_t)((COL) + 1) * 2 + 0],                    \
                       tg | (unsigned long long)__float_as_uint(a2));        \
            atomicExch(&hme[(size_t)((COL) + 1) * 2 + 1],                    \
                       tg | (unsigned long long)__float_as_uint(a3));        \
        }                                                                    \
    } while (0)

#define LOADW(M, J)                                                          \
    do {                                                                     \
        const int _j = (J);                                                  \
        Wr[M][0][0] = *(const float4*)(wr0 + _j);                            \
        Wr[M][0][1] = *(const float4*)(wr0 + _j + 4);                        \
        Wr[M][1][0] = *(const float4*)(wr1 + _j);                            \
        Wr[M][1][1] = *(const float4*)(wr1 + _j + 4);                        \
        Wr[M][2][0] = *(const float4*)(wr2 + _j);                            \
        Wr[M][2][1] = *(const float4*)(wr2 + _j + 4);                        \
        Wr[M][3][0] = *(const float4*)(wr3 + _j);                            \
        Wr[M][3][1] = *(const float4*)(wr3 + _j + 4);                        \
        Wr[M][4][0] = *(const float4*)(wr4 + _j);                            \
        Wr[M][4][1] = *(const float4*)(wr4 + _j + 4);                        \
        Wr[M][5][0] = *(const float4*)(wr5 + _j);                            \
        Wr[M][5][1] = *(const float4*)(wr5 + _j + 4);                        \
        Br[M][0][0] = *(const float4*)(br0 + _j);                            \
        Br[M][0][1] = *(const float4*)(br0 + _j + 4);                        \
        Br[M][1][0] = *(const float4*)(br1 + _j);                            \
        Br[M][1][1] = *(const float4*)(br1 + _j + 4);                        \
        Br[M][2][0] = *(const float4*)(br2 + _j);                            \
        Br[M][2][1] = *(const float4*)(br2 + _j + 4);                        \
        Br[M][3][0] = *(const float4*)(br3 + _j);                            \
        Br[M][3][1] = *(const float4*)(br3 + _j + 4);                        \
    } while (0)

// tag-check + broadcast-unpack group GIDX's halo (raw in Hg[SLOT]) into
// Hlo[BUF]/Hhi[BUF]. Off the serial chain; raw data fetched 32 cols ahead.
#define UNPACKG(GIDX, BUF, SLOT)                                             \
    do {                                                                     \
        const int _jn = (GIDX) * U;                                          \
        if (blk > 0) {                                                       \
            bool myok = (lane >= 16) ||                                      \
                ((unsigned)(Hg[SLOT] >> 32) ==                               \
                 (unsigned)(_jn + (lane >> 1) + 1));                         \
            while (__builtin_expect(!__all(myok), 0)) {                      \
                __builtin_amdgcn_s_sleep(2);                                 \
                if (lane < 16)                                               \
                    Hg[SLOT] = atomicOr(&hsrc[(size_t)_jn * 2 + lane], 0ULL);\
                myok = (lane >= 16) ||                                       \
                    ((unsigned)(Hg[SLOT] >> 32) ==                           \
                     (unsigned)(_jn + (lane >> 1) + 1));                     \
            }                                                                \
            float _hv = __uint_as_float((unsigned)(Hg[SLOT] & 0xffffffffu)); \
            _Pragma("unroll")                                                \
            for (int k = 0; k < U; ++k) {                                    \
                Hlo[BUF][k] = __shfl(_hv, 2 * k);                            \
                Hhi[BUF][k] = __shfl(_hv, 2 * k + 1);                        \
            }                                                                \
        }                                                                    \
    } while (0)

#define GROUPBODY(S)                                                         \
    do {                                                                     \
        const int G  = g4 * 4 + (S);                                         \
        const int jb = G * U;                                                \
        if (G + 1 < NGR) UNPACKG(G + 1, ((S) + 1) & 1, ((S) + 1) & 3);       \
        _Pragma("unroll")                                                    \
        for (int k = 0; k < U; ++k) COLSTEP(jb + k, (S) & 1, k);             \
        const int jw = jb + 2 * U;                                           \
        if (jw < WW) LOADW((S) & 1, jw);                                     \
        const int jh = jb + 4 * U;                                           \
        if (jh < WW && blk > 0 && lane < 16)                                 \
            Hg[S] = atomicOr(&hsrc[(size_t)jh * 2 + lane], 0ULL);            \
    } while (0)

__global__ __launch_bounds__(64, 1) void neural_grid_scan(
    const float* __restrict__ x, const float* __restrict__ w,
    const float* __restrict__ bb, float* __restrict__ out,
    unsigned long long* __restrict__ halo)
{
    const int lane = threadIdx.x;
    const int blk  = blockIdx.x;
    const int rb   = blk * (64 * R) + lane * R;     // first row of this lane

    // w rows rb-2..rb+3 (clamped; clamped rows only feed zero-valued taps)
    const float* wr0 = w + (size_t)((rb >= 2) ? rb - 2 : 0) * WW;
    const float* wr1 = w + (size_t)((rb >= 1) ? rb - 1 : 0) * WW;
    const float* wr2 = w + (size_t)rb * WW;
    const float* wr3 = w + (size_t)(rb + 1) * WW;
    const float* wr4 = w + (size_t)(rb + 2) * WW;
    const float* wr5 = w + (size_t)(rb + 3) * WW;
    const float* br0 = bb + (size_t)rb * WW;
    const float* br1 = bb + (size_t)(rb + 1) * WW;
    const float* br2 = bb + (size_t)(rb + 2) * WW;
    const float* br3 = bb + (size_t)(rb + 3) * WW;

    unsigned long long* hme  = halo + (size_t)blk * WW * 2;
    unsigned long long* hsrc = halo + (size_t)(blk - 1) * WW * 2;

    float4 xv = *(const float4*)(x + rb);
    float a0 = xv.x, a1 = xv.y, a2 = xv.z, a3 = xv.w;

    // publish initial state (column -1 == x) into slot 0, tag 1 (before gating)
    if (lane == 63) {
        atomicExch(&hme[0], (1ULL << 32) | (unsigned long long)__float_as_uint(a2));
        atomicExch(&hme[1], (1ULL << 32) | (unsigned long long)__float_as_uint(a3));
    }

    // ---- start gate: producer must be GATE columns ahead (prefetch lead 32
    // + margin for publish->visibility latency) ----
    if (blk > 0 && lane == 0) {
        while ((unsigned)(atomicOr(&hsrc[(size_t)GATE * 2], 0ULL) >> 32)
               != (unsigned)(GATE + 1)) {
            __builtin_amdgcn_s_sleep(8);
        }
    }

    float4 Wr[2][6][2], Br[2][4][2];
    unsigned long long Hg[4];
    float Hlo[2][U] = {}, Hhi[2][U] = {};

    LOADW(0, 0);
    LOADW(1, U);
    if (blk > 0 && lane < 16) {
        Hg[0] = atomicOr(&hsrc[(size_t)(0 * U) * 2 + lane], 0ULL);
        Hg[1] = atomicOr(&hsrc[(size_t)(1 * U) * 2 + lane], 0ULL);
        Hg[2] = atomicOr(&hsrc[(size_t)(2 * U) * 2 + lane], 0ULL);
        Hg[3] = atomicOr(&hsrc[(size_t)(3 * U) * 2 + lane], 0ULL);
    } else {
        Hg[0] = Hg[1] = Hg[2] = Hg[3] = 0;
    }
    UNPACKG(0, 0, 0);   // group 0 -> buf 0

    for (int g4 = 0; g4 < NGR / 4; ++g4) {
        GROUPBODY(0);
        GROUPBODY(1);
        GROUPBODY(2);
        GROUPBODY(3);
    }

    *(float4*)(out + rb) = make_float4(a0, a1, a2, a3);
}

extern "C" void kernel_launch(void* const* d_in, const int* in_sizes, int n_in,
                              void* d_out, int out_size, void* d_ws, size_t ws_size,
                              hipStream_t stream) {
    const float* x = (const float*)d_in[0];
    const float* w = (const float*)d_in[1];
    const float* b = (const float*)d_in[2];
    float* out = (float*)d_out;
    unsigned long long* halo = (unsigned long long*)d_ws;
    neural_grid_scan<<<dim3(NBLK), dim3(64), 0, stream>>>(x, w, b, out, halo);
}